// Round 1
// baseline (230.376 us; speedup 1.0000x reference)
//
#include <hip/hip_runtime.h>

#define TT 8192
#define DD 512
#define BIGU 0xFFFFFFFFu

typedef unsigned int uint;
typedef unsigned short ushort;
typedef __attribute__((ext_vector_type(8))) short short8;   // 8 bf16 = 4 VGPRs
typedef __attribute__((ext_vector_type(4))) float f32x4;

// ---- fp32 -> bf16 (RTN-even) ----
__device__ __forceinline__ uint bfr(float f) {
  uint u = __float_as_uint(f);
  return (u + 0x7FFFu + ((u >> 16) & 1u)) >> 16;
}

// fused: bf16 convert + row sum-of-squares (unchanged)
__global__ void cvtsq_kernel(const float* __restrict__ X, uint4* __restrict__ Xb,
                             float* __restrict__ sq) {
  int w = threadIdx.x >> 6, l = threadIdx.x & 63;
  int row = blockIdx.x * 4 + w;
  const float4* xr = (const float4*)(X + (size_t)row * DD) + l * 2;
  float4 a = xr[0], b = xr[1];
  uint4 o;
  o.x = bfr(a.x) | (bfr(a.y) << 16);
  o.y = bfr(a.z) | (bfr(a.w) << 16);
  o.z = bfr(b.x) | (bfr(b.y) << 16);
  o.w = bfr(b.z) | (bfr(b.w) << 16);
  Xb[(size_t)row * 64 + l] = o;
  float s = a.x * a.x + a.y * a.y + a.z * a.z + a.w * a.w +
            b.x * b.x + b.y * b.y + b.z * b.z + b.w * b.w;
#pragma unroll
  for (int off = 32; off >= 1; off >>= 1) s += __shfl_down(s, off, 64);
  if (l == 0) sq[row] = s;
}

// global->LDS async 16B
__device__ __forceinline__ void gload16(const void* g, void* l) {
  __builtin_amdgcn_global_load_lds(
      (const __attribute__((address_space(1))) void*)(size_t)g,
      (__attribute__((address_space(3))) void*)(uint)(size_t)l, 16, 0, 0);
}

// 3-term XOR chunk swizzle over 64B rows (4x16B chunks): slot s of row r holds
// source chunk s^swz(r); every 16-lane b128 read phase covers each 4-bank group
// exactly 2x (2-way aliasing = free per m136).
__device__ __forceinline__ int swz(int r) {
  return (r & 3) ^ ((r >> 1) & 2) ^ ((r >> 3) & 1);
}

__device__ __forceinline__ uint umin_(uint a, uint b) { return a < b ? a : b; }
__device__ __forceinline__ uint umax_(uint a, uint b) { return a > b ? a : b; }

// 256x256 tile, BK=64, 8 waves (2M x 4N), 4 phases/K-tile (khalf x Mhalf),
// counted vmcnt(4) at K-tile boundaries (never 0 in main loop), raw barriers,
// post-loop top-k selection epilogue (out of the k-loop critical path).
// LDS: 2 dbuf x { A[2 khalf] 16KB, B[2 khalf] 16KB } = 128 KiB.
// Slot schedule per tile t (phase p issues 1 half-tile = 2 gload16/thread):
//   p0 -> (t+1, A-k1)  [other buffer, slot dead since tile t-1 p3]
//   p1 -> (t+1, B-k1)  [other buffer]
//   p2 -> (t+2, A-k0)  [current buffer, dead after p1's barrier]
//   p3 -> (t+2, B-k0)  [current buffer, dead after p1's barrier]
// Boundary vmcnt(4): the 2 half-tiles issued at p2/p3 (4 loads) may remain in
// flight; everything tile t+1 needs is older and therefore drained.
__global__ __launch_bounds__(512, 2) void gemm_topk(
    const ushort* __restrict__ Xb, const float* __restrict__ sqv,
    uint* __restrict__ ckey) {
  __shared__ char smem[131072];

  const int t = threadIdx.x;
  const int w = t >> 6, l = t & 63;
  const int l15 = l & 15, q4 = l >> 4;
  const int wm = w >> 2, wn = w & 3;          // wave grid: 2(M) x 4(N)

  // XCD-bijective swizzle (1024 % 8 == 0) + grouped raster for L2 panel reuse
  const int bid = blockIdx.x;
  const int sw = (bid & 7) * 128 + (bid >> 3);
  const int g = sw >> 8, rr = sw & 255;
  const int bi = rr >> 3, bj = g * 8 + (rr & 7);
  const int i0 = bi * 256, j0 = bj * 256;
  const char* XbB = (const char*)Xb;

  // staging: 2 cells/thread per half-tile (1024 cells = 256 rows x 4 chunks)
  const int cell0 = w * 128 + l, cell1 = w * 128 + 64 + l;
  const int r0 = cell0 >> 2, c0 = cell0 & 3;
  const int r1 = cell1 >> 2, c1 = cell1 & 3;
  const char* sA0 = XbB + (size_t)(i0 + r0) * 1024 + (c0 ^ swz(r0)) * 16;
  const char* sA1 = XbB + (size_t)(i0 + r1) * 1024 + (c1 ^ swz(r1)) * 16;
  const char* sB0 = XbB + (size_t)(j0 + r0) * 1024 + (c0 ^ swz(r0)) * 16;
  const char* sB1 = XbB + (size_t)(j0 + r1) * 1024 + (c1 ^ swz(r1)) * 16;
  const int d0 = cell0 * 16, d1 = cell1 * 16;

  // per-lane ds_read cell offsets (within a 16KB slot)
  int aOff[2][4], bOff[4];
#pragma unroll
  for (int mh = 0; mh < 2; ++mh)
#pragma unroll
    for (int mf = 0; mf < 4; ++mf) {
      int row = wm * 128 + mh * 64 + mf * 16 + l15;
      aOff[mh][mf] = row * 64 + (q4 ^ swz(row)) * 16;
    }
#pragma unroll
  for (int nf = 0; nf < 4; ++nf) {
    int row = wn * 64 + nf * 16 + l15;
    bOff[nf] = row * 64 + (q4 ^ swz(row)) * 16;
  }

  f32x4 acc[8][4];
#pragma unroll
  for (int i = 0; i < 8; ++i)
#pragma unroll
    for (int j = 0; j < 4; ++j) {
      f32x4 z = {0.f, 0.f, 0.f, 0.f};
      acc[i][j] = z;
    }

  // prologue: stage tile0 (4 half-tiles) + tile1 A-k0,B-k0
#pragma unroll
  for (int h = 0; h < 6; ++h) {
    const int tt = h >> 2, s = h & 3;   // slot s: 0=A-k0 1=B-k0 2=A-k1 3=B-k1
    const int doff = (tt & 1) * 65536 + (s & 1) * 32768 + (s >> 1) * 16384;
    const int kb = tt * 128 + (s >> 1) * 64;
    gload16(((s & 1) ? sB0 : sA0) + kb, smem + doff + d0);
    gload16(((s & 1) ? sB1 : sA1) + kb, smem + doff + d1);
  }
  asm volatile("s_waitcnt vmcnt(4)" ::: "memory");  // tile0 landed
  __builtin_amdgcn_s_barrier();

  for (int tk = 0; tk < 8; ++tk) {
    const char* rbuf = smem + (tk & 1) * 65536;
#pragma unroll
    for (int p = 0; p < 4; ++p) {
      const int kh = p >> 1, mh = p & 1;
      const char* rbA = rbuf + kh * 16384;
      const char* rbB = rbA + 32768;
      short8 af[4], bf[4];
#pragma unroll
      for (int mf = 0; mf < 4; ++mf)
        af[mf] = *(const short8*)(rbA + aOff[mh][mf]);
#pragma unroll
      for (int nf = 0; nf < 4; ++nf)
        bf[nf] = *(const short8*)(rbB + bOff[nf]);

      {  // prefetch one half-tile per schedule (tail wraps harmlessly)
        const int s = (6 + p) & 3;                 // 2,3,0,1
        const int tt = tk + ((p < 2) ? 1 : 2);
        const int doff = (tt & 1) * 65536 + (s & 1) * 32768 + (s >> 1) * 16384;
        const int kb = (tt & 7) * 128 + (s >> 1) * 64;
        gload16(((s & 1) ? sB0 : sA0) + kb, smem + doff + d0);
        gload16(((s & 1) ? sB1 : sA1) + kb, smem + doff + d1);
      }

      __builtin_amdgcn_s_setprio(1);
#pragma unroll
      for (int mf = 0; mf < 4; ++mf)
#pragma unroll
        for (int nf = 0; nf < 4; ++nf)
          acc[mh * 4 + mf][nf] = __builtin_amdgcn_mfma_f32_16x16x32_bf16(
              af[mf], bf[nf], acc[mh * 4 + mf][nf], 0, 0, 0);
      __builtin_amdgcn_s_setprio(0);

      if (p == 3) asm volatile("s_waitcnt vmcnt(4)" ::: "memory");
      __builtin_amdgcn_s_barrier();
    }
  }

  // drain wrap DMA before overlaying LDS with the merge buffer
  asm volatile("s_waitcnt vmcnt(0)" ::: "memory");
  __builtin_amdgcn_s_barrier();
  asm volatile("" ::: "memory");

  // selection epilogue: per-lane top-2 of its 4 j-candidates per owned i-row.
  // cand[256][128], column rotated by +row for bank spread.
  uint* cand = (uint*)smem;
  float sqj[4];
  uint jglo[4];
#pragma unroll
  for (int nf = 0; nf < 4; ++nf) {
    int jg = j0 + wn * 64 + nf * 16 + l15;
    jglo[nf] = (uint)jg;
    sqj[nf] = sqv[jg];
  }
#pragma unroll
  for (int mf = 0; mf < 8; ++mf)
#pragma unroll
    for (int rg = 0; rg < 4; ++rg) {
      uint k[4];
#pragma unroll
      for (int nf = 0; nf < 4; ++nf) {
        // key = sq[j] - 2*dot (sq[i] constant per row -> order preserved)
        float key = fmaf(-2.f, acc[mf][nf][rg], sqj[nf]);
        uint u = __float_as_uint(key);
        u ^= (uint)((int)u >> 31) | 0x80000000u;   // orderable uint
        k[nf] = (u & 0xFFFFE000u) | jglo[nf];      // 19b key | 13b j
      }
      uint a = umin_(k[0], k[1]), b = umax_(k[0], k[1]);
      uint c = umin_(k[2], k[3]), d = umax_(k[2], k[3]);
      uint f1 = umin_(a, c);
      uint f2 = umin_(umax_(a, c), umin_(b, d));
      int row = wm * 128 + mf * 16 + q4 * 4 + rg;
      int col = wn * 32 + l15 * 2;
      cand[row * 128 + ((col + row) & 127)] = f1;
      cand[row * 128 + ((col + 1 + row) & 127)] = f2;
    }

  asm volatile("s_waitcnt lgkmcnt(0)" ::: "memory");
  __builtin_amdgcn_s_barrier();
  asm volatile("" ::: "memory");

  // merge: one thread per i-row scans 128 candidates -> top-4 per 256-j panel
  if (t < 256) {
    uint best[4] = {BIGU, BIGU, BIGU, BIGU};
    const uint* rp = cand + t * 128;
#pragma unroll 4
    for (int u = 0; u < 128; ++u) {
      uint p = rp[(u + t) & 127];   // rotated visit: conflict-free, order-free
      if (p < best[3]) {
        best[3] = p;
#pragma unroll
        for (int x = 3; x >= 1; --x) {
          uint lo = best[x - 1], hi = best[x];
          bool swp = hi < lo;
          best[x - 1] = swp ? hi : lo;
          best[x] = swp ? lo : hi;
        }
      }
    }
    uint* op = ckey + (size_t)(i0 + t) * 128 + bj * 4;
    op[0] = best[0];
    op[1] = best[1];
    op[2] = best[2];
    op[3] = best[3];
  }
}

// fused: LDS rank-count top-8 of 128 candidates, exact fp64 re-rank,
// interpolate + write. 4 rows per 256-thread block (one wave per row). Unchanged.
__global__ __launch_bounds__(256) void refine_gen(
    const float* __restrict__ X, const uint* __restrict__ ckey,
    const float* __restrict__ gaps, const int* __restrict__ nnc,
    float* __restrict__ out) {
  __shared__ uint keys[4][128];
  __shared__ uint seln[4][8];
  const int w = threadIdx.x >> 6, l = threadIdx.x & 63;
  const int row = blockIdx.x * 4 + w;
  uint k0 = ckey[(size_t)row * 128 + l];
  uint k1 = ckey[(size_t)row * 128 + 64 + l];
  keys[w][l] = k0;
  keys[w][64 + l] = k1;
  __syncthreads();

  int r0 = 0, r1 = 0;
  const uint4* kk = (const uint4*)keys[w];
#pragma unroll
  for (int i = 0; i < 32; ++i) {
    uint4 v = kk[i];
    r0 += (v.x < k0) + (v.y < k0) + (v.z < k0) + (v.w < k0);
    r1 += (v.x < k1) + (v.y < k1) + (v.z < k1) + (v.w < k1);
  }
  if (r0 < 8) seln[w][r0] = k0 & 8191u;
  if (r1 < 8) seln[w][r1] = k1 & 8191u;
  __syncthreads();

  int selj[8];
#pragma unroll
  for (int s = 0; s < 8; ++s) selj[s] = (int)seln[w][s];

  float xi[8];
  const float4* xr = (const float4*)(X + (size_t)row * DD) + l * 2;
  float4 xa = xr[0], xb = xr[1];
  xi[0] = xa.x; xi[1] = xa.y; xi[2] = xa.z; xi[3] = xa.w;
  xi[4] = xb.x; xi[5] = xb.y; xi[6] = xb.z; xi[7] = xb.w;

  float yv[8][8];
  double ex[8];
#pragma unroll
  for (int s = 0; s < 8; ++s) {
    const float4* yr = (const float4*)(X + (size_t)selj[s] * DD) + l * 2;
    float4 ya = yr[0], yb = yr[1];
    yv[s][0] = ya.x; yv[s][1] = ya.y; yv[s][2] = ya.z; yv[s][3] = ya.w;
    yv[s][4] = yb.x; yv[s][5] = yb.y; yv[s][6] = yb.z; yv[s][7] = yb.w;
    double a = 0.0;
#pragma unroll
    for (int m = 0; m < 8; ++m) {
      double df = (double)xi[m] - (double)yv[s][m];
      a += df * df;
    }
#pragma unroll
    for (int off = 32; off >= 1; off >>= 1) a += __shfl_down(a, off, 64);
    ex[s] = __shfl(a, 0, 64);
  }

  int rk[8];
#pragma unroll
  for (int s = 0; s < 8; ++s) {
    int r = 0;
#pragma unroll
    for (int u = 0; u < 8; ++u)
      if (ex[u] < ex[s] || (ex[u] == ex[s] && selj[u] < selj[s])) ++r;
    rk[s] = r;
  }

#pragma unroll
  for (int o = 0; o < 4; ++o) {
    float g = gaps[row * 4 + o];
    int target = nnc[row * 4 + o] + 1;
    float ys[8];
#pragma unroll
    for (int m = 0; m < 8; ++m) ys[m] = 0.f;
#pragma unroll
    for (int s = 0; s < 8; ++s) {
      bool hit = (rk[s] == target);
#pragma unroll
      for (int m = 0; m < 8; ++m) ys[m] = hit ? yv[s][m] : ys[m];
    }
    float4 r0v, r1v;
    r0v.x = fmaf(g, ys[0] - xi[0], xi[0]);
    r0v.y = fmaf(g, ys[1] - xi[1], xi[1]);
    r0v.z = fmaf(g, ys[2] - xi[2], xi[2]);
    r0v.w = fmaf(g, ys[3] - xi[3], xi[3]);
    r1v.x = fmaf(g, ys[4] - xi[4], xi[4]);
    r1v.y = fmaf(g, ys[5] - xi[5], xi[5]);
    r1v.z = fmaf(g, ys[6] - xi[6], xi[6]);
    r1v.w = fmaf(g, ys[7] - xi[7], xi[7]);
    float4* dst = (float4*)(out + ((size_t)row * 4 + o) * DD) + l * 2;
    dst[0] = r0v;
    dst[1] = r1v;
  }
}

extern "C" void kernel_launch(void* const* d_in, const int* in_sizes, int n_in,
                              void* d_out, int out_size, void* d_ws, size_t ws_size,
                              hipStream_t stream) {
  const float* X = (const float*)d_in[0];
  const float* gaps = (const float*)d_in[1];
  const int* nnc = (const int*)d_in[2];
  float* out = (float*)d_out;

  float* sqv = (float*)d_ws;                                  // 32 KB
  uint4* Xb4 = (uint4*)((char*)d_ws + 32768);                 // 8 MB bf16 X
  uint* ckey = (uint*)((char*)d_ws + 32768 + 8388608);        // 4 MB candidates

  cvtsq_kernel<<<TT / 4, 256, 0, stream>>>(X, Xb4, sqv);
  gemm_topk<<<1024, 512, 0, stream>>>((const ushort*)Xb4, sqv, ckey);
  refine_gen<<<TT / 4, 256, 0, stream>>>(X, ckey, gaps, nnc, out);
}

// Round 2
// 206.905 us; speedup vs baseline: 1.1134x; 1.1134x over previous
//
#include <hip/hip_runtime.h>

#define TT 8192
#define DD 512
#define NN 4
#define JS 16
#define JR (TT / JS)        // 512 columns per slice
#define BIGU 0xFFFFFFFFu

typedef unsigned int uint;
typedef unsigned short ushort;
typedef __attribute__((ext_vector_type(8))) short short8;   // 8 bf16 = 4 VGPRs
typedef __attribute__((ext_vector_type(4))) float f32x4;

// ---- fp32 -> bf16 (RTN-even) ----
__device__ __forceinline__ uint bfr(float f) {
  uint u = __float_as_uint(f);
  return (u + 0x7FFFu + ((u >> 16) & 1u)) >> 16;
}

// fused: bf16 convert + row sum-of-squares
__global__ void cvtsq_kernel(const float* __restrict__ X, uint4* __restrict__ Xb,
                             float* __restrict__ sq) {
  int w = threadIdx.x >> 6, l = threadIdx.x & 63;
  int row = blockIdx.x * 4 + w;
  const float4* xr = (const float4*)(X + (size_t)row * DD) + l * 2;
  float4 a = xr[0], b = xr[1];
  uint4 o;
  o.x = bfr(a.x) | (bfr(a.y) << 16);
  o.y = bfr(a.z) | (bfr(a.w) << 16);
  o.z = bfr(b.x) | (bfr(b.y) << 16);
  o.w = bfr(b.z) | (bfr(b.w) << 16);
  Xb[(size_t)row * 64 + l] = o;
  float s = a.x * a.x + a.y * a.y + a.z * a.z + a.w * a.w +
            b.x * b.x + b.y * b.y + b.z * b.z + b.w * b.w;
#pragma unroll
  for (int off = 32; off >= 1; off >>= 1) s += __shfl_down(s, off, 64);
  if (l == 0) sq[row] = s;
}

// global->LDS async 16B
__device__ __forceinline__ void gload16(const void* g, void* l) {
  __builtin_amdgcn_global_load_lds(
      (const __attribute__((address_space(1))) void*)(size_t)g,
      (__attribute__((address_space(3))) void*)(uint)(size_t)l, 16, 0, 0);
}

// 3-term XOR swizzle: row r (64B = 4x16B chunks), slot s holds source chunk s^g(r).
// Guarantees every 16-lane b128 read phase covers each 4-bank group exactly 2x.
__device__ __forceinline__ int swz(int r) {
  return (r & 3) ^ ((r >> 1) & 2) ^ ((r >> 3) & 1);
}

// bf16-MFMA distance GEMM (transposed: m=j, n=i), 128x128 tile, BK=32,
// double-buffered LDS (2x16KB, 1 barrier/stage, cross-stage DMA prefetch),
// in-register per-row top-4/lane streaming selection
__global__ __launch_bounds__(256, 4) void gemm_topk(
    const ushort* __restrict__ Xb, const float* __restrict__ sqv,
    uint* __restrict__ ckey) {
  __shared__ char smem[32768];        // 2 stage buffers; merge overlays

  const int t = threadIdx.x;
  const int w = t >> 6, l = t & 63;
  const int l15 = l & 15, q4 = l >> 4;
  const int bi = blockIdx.x >> 4;     // 64 row-blocks of 128 i-rows
  const int bs = blockIdx.x & 15;     // 16 j-slices
  const int i0 = bi * 128;
  const int js0 = bs * JR;
  const char* XbB = (const char*)Xb;
  const int mq = (w & 1) * 64;        // wave's j-quadrant
  const int nq = (w >> 1) * 64;       // wave's i-quadrant

  // loop-invariant staging addresses: 4 chunks/thread per stage
  // cells 0..511 = 128 i-rows x 4 slots; cells 512..1023 = 128 j-rows x 4 slots
  const char* gQ[4];
#pragma unroll
  for (int q = 0; q < 4; ++q) {
    int cidx = q * 256 + t;
    int r = cidx >> 2, slot = cidx & 3;
    int cs = slot ^ swz(r);
    int rowg = (r < 128) ? (i0 + r) : (js0 + r - 128);
    gQ[q] = XbB + (size_t)rowg * 1024 + cs * 16;
  }

  uint L[4][4];                       // per-(lane, i-frag) top-4 packed keys
#pragma unroll
  for (int cb = 0; cb < 4; ++cb)
#pragma unroll
    for (int s = 0; s < 4; ++s) L[cb][s] = BIGU;

  f32x4 acc[4][4];
#pragma unroll
  for (int rb = 0; rb < 4; ++rb)
#pragma unroll
    for (int cb = 0; cb < 4; ++cb) {
      f32x4 z = {0.f, 0.f, 0.f, 0.f};
      acc[rb][cb] = z;
    }

  {  // prologue: DMA stage 0 into buf0
#pragma unroll
    for (int q = 0; q < 4; ++q)
      gload16(gQ[q], smem + (q * 256 + t) * 16);
  }

  // per-lane LDS read cells (loop-invariant except buffer base)
  int cellA[4], cellB[4];
#pragma unroll
  for (int rb = 0; rb < 4; ++rb) {
    int rj = 128 + mq + rb * 16 + l15;
    cellA[rb] = rj * 4 + (q4 ^ swz(rj));
  }
#pragma unroll
  for (int cb = 0; cb < 4; ++cb) {
    int ri = nq + cb * 16 + l15;
    cellB[cb] = ri * 4 + (q4 ^ swz(ri));
  }

  for (int s = 0; s < 64; ++s) {      // 4 j-tiles x 16 k-stages, linearized
    const int kt = s & 15, jt = s >> 4;
    __syncthreads();                  // drains stage-s DMA; fences buf^1 readers

    {  // prefetch stage s+1 into the other buffer (wraps harmlessly at s=63)
      const int sn = (s + 1) & 63;
      const int ioff = (sn & 15) * 64;
      const int joff = ioff + (sn >> 4) * 131072;
      char* dbase = smem + ((s + 1) & 1) * 16384;
#pragma unroll
      for (int q = 0; q < 4; ++q)
        gload16(gQ[q] + (q < 2 ? ioff : joff), dbase + (q * 256 + t) * 16);
    }

    {  // compute stage s from current buffer (one 16x16x32 k-step)
      const char* base = smem + (s & 1) * 16384;
      short8 af[4], bf[4];
#pragma unroll
      for (int rb = 0; rb < 4; ++rb)
        af[rb] = *(const short8*)(base + cellA[rb] * 16);
#pragma unroll
      for (int cb = 0; cb < 4; ++cb)
        bf[cb] = *(const short8*)(base + cellB[cb] * 16);
#pragma unroll
      for (int rb = 0; rb < 4; ++rb)
#pragma unroll
        for (int cb = 0; cb < 4; ++cb)
          acc[rb][cb] = __builtin_amdgcn_mfma_f32_16x16x32_bf16(
              af[rb], bf[cb], acc[rb][cb], 0, 0, 0);
    }

    if (kt == 15) {                   // per-j-tile selection epilogue
      const int jb = js0 + jt * 128;
      // key = sq[j] - 2*dot; D layout: col(lane&15)=i-local, row(q4*4+reg)=j-local
#pragma unroll
      for (int rb = 0; rb < 4; ++rb) {
        int jg = jb + mq + rb * 16 + q4 * 4;
        float4 sj = *(const float4*)(sqv + jg);
        float s4[4] = {sj.x, sj.y, sj.z, sj.w};
#pragma unroll
        for (int cb = 0; cb < 4; ++cb) {
#pragma unroll
          for (int r = 0; r < 4; ++r) {
            float key = fmaf(-2.f, acc[rb][cb][r], s4[r]);
            uint u = __float_as_uint(key);
            u ^= (uint)((int)u >> 31) | 0x80000000u;       // orderable uint
            uint p = (u & 0xFFFFE000u) | (uint)(jg + r);   // 19b key | 13b j
            if (p < L[cb][3]) {
              L[cb][3] = p;
#pragma unroll
              for (int x = 3; x >= 1; --x) {
                uint lo = L[cb][x - 1], hi = L[cb][x];
                bool sw = hi < lo;
                L[cb][x - 1] = sw ? hi : lo;
                L[cb][x] = sw ? lo : hi;
              }
            }
          }
        }
      }
      // re-zero accumulators for next j-tile
#pragma unroll
      for (int rb = 0; rb < 4; ++rb)
#pragma unroll
        for (int cb = 0; cb < 4; ++cb) {
          f32x4 z = {0.f, 0.f, 0.f, 0.f};
          acc[rb][cb] = z;
        }
    }
  }

  __syncthreads();                     // drains wrap DMA; overlay merge buffer
  uint* ml = (uint*)smem;              // [128 rows][33]
  const int cid = (w & 1) * 4 + q4;    // 8 contributors per row
#pragma unroll
  for (int cb = 0; cb < 4; ++cb) {
    int n = nq + cb * 16 + l15;
#pragma unroll
    for (int s = 0; s < 4; ++s) ml[n * 33 + cid * 4 + s] = L[cb][s];
  }
  __syncthreads();
  if (t < 128) {
    uint best[8];
#pragma unroll
    for (int s = 0; s < 8; ++s) best[s] = BIGU;
    for (int u = 0; u < 32; ++u) {
      uint p = ml[t * 33 + u];
      if (p < best[7]) {
        best[7] = p;
#pragma unroll
        for (int s = 7; s >= 1; --s) {
          uint lo = best[s - 1], hi = best[s];
          bool sw = hi < lo;
          best[s - 1] = sw ? hi : lo;
          best[s] = sw ? lo : hi;
        }
      }
    }
#pragma unroll
    for (int s = 0; s < 8; ++s)
      ckey[(size_t)(i0 + t) * 128 + bs * 8 + s] = best[s];
  }
}

// refine v2: group-parallel exact fp64 re-rank.
// One wave per row. 8 groups x 8 lanes: group g computes the distance to
// candidate g in parallel (no serial 6-step fp64 wave chains, no yv[8][8]
// register block). Interpolation re-gathers only the 4 chosen rows,
// wave-uniform coalesced.
__global__ __launch_bounds__(256) void refine_gen(
    const float* __restrict__ X, const uint* __restrict__ ckey,
    const float* __restrict__ gaps, const int* __restrict__ nnc,
    float* __restrict__ out) {
  __shared__ uint keys[4][128];
  __shared__ uint seln[4][8];
  const int w = threadIdx.x >> 6, l = threadIdx.x & 63;
  const int row = blockIdx.x * 4 + w;

  uint k0 = ckey[(size_t)row * 128 + l];
  uint k1 = ckey[(size_t)row * 128 + 64 + l];
  keys[w][l] = k0;
  keys[w][64 + l] = k1;

  // own-row fragment for interpolation (lane owns floats [8l, 8l+8))
  const float4* xr = (const float4*)(X + (size_t)row * DD) + l * 2;
  float4 xa = xr[0], xb = xr[1];

  __syncthreads();

  // exact rank of each key among the 128 (keys unique) -> top-8 candidates
  int r0 = 0, r1 = 0;
  const uint4* kk = (const uint4*)keys[w];
#pragma unroll
  for (int i = 0; i < 32; ++i) {
    uint4 v = kk[i];
    r0 += (v.x < k0) + (v.y < k0) + (v.z < k0) + (v.w < k0);
    r1 += (v.x < k1) + (v.y < k1) + (v.z < k1) + (v.w < k1);
  }
  if (r0 < 8) seln[w][r0] = k0 & 8191u;
  if (r1 < 8) seln[w][r1] = k1 & 8191u;
  __syncthreads();

  int selj[8];
#pragma unroll
  for (int s = 0; s < 8; ++s) selj[s] = (int)seln[w][s];

  // group-parallel fp64 distance: group g (lanes 8g..8g+7) -> candidate g.
  // Own-row re-read from global: the same 128B lines are read by all 8
  // groups -> L1-hot after first touch.
  const int q = l & 7;
  const float* yrow = X + (size_t)selj[l >> 3] * DD;
  const float* xrow = X + (size_t)row * DD;
  double a = 0.0;
#pragma unroll
  for (int k = 0; k < 16; ++k) {
    float4 y4 = ((const float4*)yrow)[k * 8 + q];
    float4 x4 = ((const float4*)xrow)[k * 8 + q];
    double d0 = (double)x4.x - (double)y4.x;
    double d1 = (double)x4.y - (double)y4.y;
    double d2 = (double)x4.z - (double)y4.z;
    double d3 = (double)x4.w - (double)y4.w;
    a += d0 * d0 + d1 * d1 + d2 * d2 + d3 * d3;
  }
  // 3-step reduce within the 8-lane group (full sum lands at lane q==0)
  a += __shfl_down(a, 4, 8);
  a += __shfl_down(a, 2, 8);
  a += __shfl_down(a, 1, 8);

  // broadcast the 8 group sums to every lane
  double ex[8];
#pragma unroll
  for (int s = 0; s < 8; ++s) ex[s] = __shfl(a, s * 8, 64);

  int rk[8];                           // exact ranks (rank 0 = self)
#pragma unroll
  for (int s = 0; s < 8; ++s) {
    int r = 0;
#pragma unroll
    for (int u = 0; u < 8; ++u)
      if (ex[u] < ex[s] || (ex[u] == ex[s] && selj[u] < selj[s])) ++r;
    rk[s] = r;
  }

  // choose the 4 target rows up-front (wave-uniform), then gather + interp
  int jsel[4];
  float gv[4];
#pragma unroll
  for (int o = 0; o < 4; ++o) {
    gv[o] = gaps[row * 4 + o];
    int target = nnc[row * 4 + o] + 1;   // skip self (rank 0)
    int js = 0;
#pragma unroll
    for (int s = 0; s < 8; ++s) js = (rk[s] == target) ? selj[s] : js;
    jsel[o] = js;
  }

#pragma unroll
  for (int o = 0; o < 4; ++o) {
    const float4* yr = (const float4*)(X + (size_t)jsel[o] * DD) + l * 2;
    float4 ya = yr[0], yb = yr[1];
    float gp = gv[o];
    float4 r0v, r1v;
    r0v.x = fmaf(gp, ya.x - xa.x, xa.x);
    r0v.y = fmaf(gp, ya.y - xa.y, xa.y);
    r0v.z = fmaf(gp, ya.z - xa.z, xa.z);
    r0v.w = fmaf(gp, ya.w - xa.w, xa.w);
    r1v.x = fmaf(gp, yb.x - xb.x, xb.x);
    r1v.y = fmaf(gp, yb.y - xb.y, xb.y);
    r1v.z = fmaf(gp, yb.z - xb.z, xb.z);
    r1v.w = fmaf(gp, yb.w - xb.w, xb.w);
    float4* dst = (float4*)(out + ((size_t)row * 4 + o) * DD) + l * 2;
    dst[0] = r0v;
    dst[1] = r1v;
  }
}

extern "C" void kernel_launch(void* const* d_in, const int* in_sizes, int n_in,
                              void* d_out, int out_size, void* d_ws, size_t ws_size,
                              hipStream_t stream) {
  const float* X = (const float*)d_in[0];
  const float* gaps = (const float*)d_in[1];
  const int* nnc = (const int*)d_in[2];
  float* out = (float*)d_out;

  float* sqv = (float*)d_ws;                                  // 32 KB
  uint4* Xb4 = (uint4*)((char*)d_ws + 32768);                 // 8 MB bf16 X
  uint* ckey = (uint*)((char*)d_ws + 32768 + 8388608);        // 4 MB candidates

  cvtsq_kernel<<<TT / 4, 256, 0, stream>>>(X, Xb4, sqv);
  gemm_topk<<<1024, 256, 0, stream>>>((const ushort*)Xb4, sqv, ckey);
  refine_gen<<<TT / 4, 256, 0, stream>>>(X, ckey, gaps, nnc, out);
}

// Round 3
// 205.526 us; speedup vs baseline: 1.1209x; 1.0067x over previous
//
#include <hip/hip_runtime.h>

#define TT 8192
#define DD 512
#define NN 4
#define JS 16
#define JR (TT / JS)        // 512 columns per slice
#define BIGU 0xFFFFFFFFu

typedef unsigned int uint;
typedef unsigned short ushort;
typedef __attribute__((ext_vector_type(8))) short short8;   // 8 bf16 = 4 VGPRs
typedef __attribute__((ext_vector_type(4))) float f32x4;

// ---- fp32 -> bf16 (RTN-even) ----
__device__ __forceinline__ uint bfr(float f) {
  uint u = __float_as_uint(f);
  return (u + 0x7FFFu + ((u >> 16) & 1u)) >> 16;
}

// fused: bf16 convert + row sum-of-squares
__global__ void cvtsq_kernel(const float* __restrict__ X, uint4* __restrict__ Xb,
                             float* __restrict__ sq) {
  int w = threadIdx.x >> 6, l = threadIdx.x & 63;
  int row = blockIdx.x * 4 + w;
  const float4* xr = (const float4*)(X + (size_t)row * DD) + l * 2;
  float4 a = xr[0], b = xr[1];
  uint4 o;
  o.x = bfr(a.x) | (bfr(a.y) << 16);
  o.y = bfr(a.z) | (bfr(a.w) << 16);
  o.z = bfr(b.x) | (bfr(b.y) << 16);
  o.w = bfr(b.z) | (bfr(b.w) << 16);
  Xb[(size_t)row * 64 + l] = o;
  float s = a.x * a.x + a.y * a.y + a.z * a.z + a.w * a.w +
            b.x * b.x + b.y * b.y + b.z * b.z + b.w * b.w;
#pragma unroll
  for (int off = 32; off >= 1; off >>= 1) s += __shfl_down(s, off, 64);
  if (l == 0) sq[row] = s;
}

// global->LDS async 16B
__device__ __forceinline__ void gload16(const void* g, void* l) {
  __builtin_amdgcn_global_load_lds(
      (const __attribute__((address_space(1))) void*)(size_t)g,
      (__attribute__((address_space(3))) void*)(uint)(size_t)l, 16, 0, 0);
}

// 3-term XOR swizzle: row r (64B = 4x16B chunks), slot s holds source chunk s^g(r).
// Guarantees every 16-lane b128 read phase covers each 4-bank group exactly 2x.
__device__ __forceinline__ int swz(int r) {
  return (r & 3) ^ ((r >> 1) & 2) ^ ((r >> 3) & 1);
}

// bf16-MFMA distance GEMM (transposed: m=j, n=i), 128x128 tile, BK=32,
// double-buffered LDS (2x16KB), split-barrier counted-vmcnt pipeline:
// per stage {B1; issue P(s+1); vmcnt(4) [P(s) landed, P(s+1) in flight]; B2;
// compute(s)} — the DMA queue never drains in the main loop.
__global__ __launch_bounds__(256, 4) void gemm_topk(
    const ushort* __restrict__ Xb, const float* __restrict__ sqv,
    uint* __restrict__ ckey) {
  __shared__ char smem[32768];        // 2 stage buffers; merge overlays

  const int t = threadIdx.x;
  const int w = t >> 6, l = t & 63;
  const int l15 = l & 15, q4 = l >> 4;
  // XCD-bijective swizzle: each XCD owns 8 i-panels (all 16 slices) -> the
  // panel stays L2-resident per XCD. 1024 % 8 == 0 -> bijective.
  const int bid = (blockIdx.x & 7) * 128 + (blockIdx.x >> 3);
  const int bi = bid >> 4;            // 64 row-blocks of 128 i-rows
  const int bs = bid & 15;            // 16 j-slices
  const int i0 = bi * 128;
  const int js0 = bs * JR;
  const char* XbB = (const char*)Xb;
  const int mq = (w & 1) * 64;        // wave's j-quadrant
  const int nq = (w >> 1) * 64;       // wave's i-quadrant

  // loop-invariant staging addresses: 4 chunks/thread per stage
  // cells 0..511 = 128 i-rows x 4 slots; cells 512..1023 = 128 j-rows x 4 slots
  const char* gQ[4];
#pragma unroll
  for (int q = 0; q < 4; ++q) {
    int cidx = q * 256 + t;
    int r = cidx >> 2, slot = cidx & 3;
    int cs = slot ^ swz(r);
    int rowg = (r < 128) ? (i0 + r) : (js0 + r - 128);
    gQ[q] = XbB + (size_t)rowg * 1024 + cs * 16;
  }

  uint L[4][4];                       // per-(lane, i-frag) top-4 packed keys
#pragma unroll
  for (int cb = 0; cb < 4; ++cb)
#pragma unroll
    for (int s = 0; s < 4; ++s) L[cb][s] = BIGU;

  f32x4 acc[4][4];
#pragma unroll
  for (int rb = 0; rb < 4; ++rb)
#pragma unroll
    for (int cb = 0; cb < 4; ++cb) {
      f32x4 z = {0.f, 0.f, 0.f, 0.f};
      acc[rb][cb] = z;
    }

  {  // prologue: DMA stage 0 into buf0
#pragma unroll
    for (int q = 0; q < 4; ++q)
      gload16(gQ[q], smem + (q * 256 + t) * 16);
  }
  asm volatile("" ::: "memory");

  // per-lane LDS read cells (loop-invariant except buffer base)
  int cellA[4], cellB[4];
#pragma unroll
  for (int rb = 0; rb < 4; ++rb) {
    int rj = 128 + mq + rb * 16 + l15;
    cellA[rb] = rj * 4 + (q4 ^ swz(rj));
  }
#pragma unroll
  for (int cb = 0; cb < 4; ++cb) {
    int ri = nq + cb * 16 + l15;
    cellB[cb] = ri * 4 + (q4 ^ swz(ri));
  }

  for (int s = 0; s < 64; ++s) {      // 4 j-tiles x 16 k-stages, linearized
    const int kt = s & 15, jt = s >> 4;

    // B1: all waves finished compute(s-1) -> safe to overwrite buf[(s+1)&1]
    __builtin_amdgcn_s_barrier();
    asm volatile("" ::: "memory");

    {  // issue prefetch stage s+1 into the other buffer (wraps at s=63)
      const int sn = (s + 1) & 63;
      const int ioff = (sn & 15) * 64;
      const int joff = ioff + (sn >> 4) * 131072;
      char* dbase = smem + ((s + 1) & 1) * 16384;
#pragma unroll
      for (int q = 0; q < 4; ++q)
        gload16(gQ[q] + (q < 2 ? ioff : joff), dbase + (q * 256 + t) * 16);
    }

    // wait for MY stage-s loads (oldest 4); stage-(s+1) loads stay in flight
    asm volatile("s_waitcnt vmcnt(4)" ::: "memory");
    // B2: everyone's stage-s DMA has landed
    __builtin_amdgcn_s_barrier();
    asm volatile("" ::: "memory");

    {  // compute stage s from current buffer (one 16x16x32 k-step)
      const char* base = smem + (s & 1) * 16384;
      short8 af[4], bf[4];
#pragma unroll
      for (int rb = 0; rb < 4; ++rb)
        af[rb] = *(const short8*)(base + cellA[rb] * 16);
#pragma unroll
      for (int cb = 0; cb < 4; ++cb)
        bf[cb] = *(const short8*)(base + cellB[cb] * 16);
#pragma unroll
      for (int rb = 0; rb < 4; ++rb)
#pragma unroll
        for (int cb = 0; cb < 4; ++cb)
          acc[rb][cb] = __builtin_amdgcn_mfma_f32_16x16x32_bf16(
              af[rb], bf[cb], acc[rb][cb], 0, 0, 0);
    }

    if (kt == 15) {                   // per-j-tile selection epilogue
      const int jb = js0 + jt * 128;
      // key = sq[j] - 2*dot; D layout: col(lane&15)=i-local, row(q4*4+reg)=j-local
#pragma unroll
      for (int rb = 0; rb < 4; ++rb) {
        int jg = jb + mq + rb * 16 + q4 * 4;
        float4 sj = *(const float4*)(sqv + jg);
        float s4[4] = {sj.x, sj.y, sj.z, sj.w};
#pragma unroll
        for (int cb = 0; cb < 4; ++cb) {
#pragma unroll
          for (int r = 0; r < 4; ++r) {
            float key = fmaf(-2.f, acc[rb][cb][r], s4[r]);
            uint u = __float_as_uint(key);
            u ^= (uint)((int)u >> 31) | 0x80000000u;       // orderable uint
            uint p = (u & 0xFFFFE000u) | (uint)(jg + r);   // 19b key | 13b j
            if (p < L[cb][3]) {
              L[cb][3] = p;
#pragma unroll
              for (int x = 3; x >= 1; --x) {
                uint lo = L[cb][x - 1], hi = L[cb][x];
                bool sw = hi < lo;
                L[cb][x - 1] = sw ? hi : lo;
                L[cb][x] = sw ? lo : hi;
              }
            }
          }
        }
      }
      // re-zero accumulators for next j-tile
#pragma unroll
      for (int rb = 0; rb < 4; ++rb)
#pragma unroll
        for (int cb = 0; cb < 4; ++cb) {
          f32x4 z = {0.f, 0.f, 0.f, 0.f};
          acc[rb][cb] = z;
        }
    }
  }

  // drain wrap DMA before overlaying LDS with the merge buffer
  asm volatile("s_waitcnt vmcnt(0)" ::: "memory");
  __builtin_amdgcn_s_barrier();
  asm volatile("" ::: "memory");

  uint* ml = (uint*)smem;              // [128 rows][33]
  const int cid = (w & 1) * 4 + q4;    // 8 contributors per row
#pragma unroll
  for (int cb = 0; cb < 4; ++cb) {
    int n = nq + cb * 16 + l15;
#pragma unroll
    for (int s = 0; s < 4; ++s) ml[n * 33 + cid * 4 + s] = L[cb][s];
  }
  __syncthreads();
  if (t < 128) {
    uint best[8];
#pragma unroll
    for (int s = 0; s < 8; ++s) best[s] = BIGU;
    for (int u = 0; u < 32; ++u) {
      uint p = ml[t * 33 + u];
      if (p < best[7]) {
        best[7] = p;
#pragma unroll
        for (int s = 7; s >= 1; --s) {
          uint lo = best[s - 1], hi = best[s];
          bool sw = hi < lo;
          best[s - 1] = sw ? hi : lo;
          best[s] = sw ? lo : hi;
        }
      }
    }
#pragma unroll
    for (int s = 0; s < 8; ++s)
      ckey[(size_t)(i0 + t) * 128 + bs * 8 + s] = best[s];
  }
}

// refine v2.1: group-parallel exact fp64 re-rank; candidate row index read
// from LDS (seln) instead of a runtime-indexed private array (scratch fix).
__global__ __launch_bounds__(256) void refine_gen(
    const float* __restrict__ X, const uint* __restrict__ ckey,
    const float* __restrict__ gaps, const int* __restrict__ nnc,
    float* __restrict__ out) {
  __shared__ uint keys[4][128];
  __shared__ uint seln[4][8];
  const int w = threadIdx.x >> 6, l = threadIdx.x & 63;
  const int row = blockIdx.x * 4 + w;

  uint k0 = ckey[(size_t)row * 128 + l];
  uint k1 = ckey[(size_t)row * 128 + 64 + l];
  keys[w][l] = k0;
  keys[w][64 + l] = k1;

  // own-row fragment for interpolation (lane owns floats [8l, 8l+8))
  const float4* xr = (const float4*)(X + (size_t)row * DD) + l * 2;
  float4 xa = xr[0], xb = xr[1];

  __syncthreads();

  // exact rank of each key among the 128 (keys unique) -> top-8 candidates
  int r0 = 0, r1 = 0;
  const uint4* kk = (const uint4*)keys[w];
#pragma unroll
  for (int i = 0; i < 32; ++i) {
    uint4 v = kk[i];
    r0 += (v.x < k0) + (v.y < k0) + (v.z < k0) + (v.w < k0);
    r1 += (v.x < k1) + (v.y < k1) + (v.z < k1) + (v.w < k1);
  }
  if (r0 < 8) seln[w][r0] = k0 & 8191u;
  if (r1 < 8) seln[w][r1] = k1 & 8191u;
  __syncthreads();

  int selj[8];
#pragma unroll
  for (int s = 0; s < 8; ++s) selj[s] = (int)seln[w][s];  // static-index uses

  // group-parallel fp64 distance: group g (lanes 8g..8g+7) -> candidate g.
  // Candidate index via LDS read (runtime index on a private array would
  // spill the array to scratch).
  const int q = l & 7;
  const float* yrow = X + (size_t)seln[w][l >> 3] * DD;
  const float* xrow = X + (size_t)row * DD;
  double a = 0.0;
#pragma unroll
  for (int k = 0; k < 16; ++k) {
    float4 y4 = ((const float4*)yrow)[k * 8 + q];
    float4 x4 = ((const float4*)xrow)[k * 8 + q];
    double d0 = (double)x4.x - (double)y4.x;
    double d1 = (double)x4.y - (double)y4.y;
    double d2 = (double)x4.z - (double)y4.z;
    double d3 = (double)x4.w - (double)y4.w;
    a += d0 * d0 + d1 * d1 + d2 * d2 + d3 * d3;
  }
  // 3-step reduce within the 8-lane group (full sum lands at lane q==0)
  a += __shfl_down(a, 4, 8);
  a += __shfl_down(a, 2, 8);
  a += __shfl_down(a, 1, 8);

  // broadcast the 8 group sums to every lane
  double ex[8];
#pragma unroll
  for (int s = 0; s < 8; ++s) ex[s] = __shfl(a, s * 8, 64);

  int rk[8];                           // exact ranks (rank 0 = self)
#pragma unroll
  for (int s = 0; s < 8; ++s) {
    int r = 0;
#pragma unroll
    for (int u = 0; u < 8; ++u)
      if (ex[u] < ex[s] || (ex[u] == ex[s] && selj[u] < selj[s])) ++r;
    rk[s] = r;
  }

  // choose the 4 target rows up-front (wave-uniform), then gather + interp
  int jsel[4];
  float gv[4];
#pragma unroll
  for (int o = 0; o < 4; ++o) {
    gv[o] = gaps[row * 4 + o];
    int target = nnc[row * 4 + o] + 1;   // skip self (rank 0)
    int js = 0;
#pragma unroll
    for (int s = 0; s < 8; ++s) js = (rk[s] == target) ? selj[s] : js;
    jsel[o] = js;
  }

#pragma unroll
  for (int o = 0; o < 4; ++o) {
    const float4* yr = (const float4*)(X + (size_t)jsel[o] * DD) + l * 2;
    float4 ya = yr[0], yb = yr[1];
    float gp = gv[o];
    float4 r0v, r1v;
    r0v.x = fmaf(gp, ya.x - xa.x, xa.x);
    r0v.y = fmaf(gp, ya.y - xa.y, xa.y);
    r0v.z = fmaf(gp, ya.z - xa.z, xa.z);
    r0v.w = fmaf(gp, ya.w - xa.w, xa.w);
    r1v.x = fmaf(gp, yb.x - xb.x, xb.x);
    r1v.y = fmaf(gp, yb.y - xb.y, xb.y);
    r1v.z = fmaf(gp, yb.z - xb.z, xb.z);
    r1v.w = fmaf(gp, yb.w - xb.w, xb.w);
    float4* dst = (float4*)(out + ((size_t)row * 4 + o) * DD) + l * 2;
    dst[0] = r0v;
    dst[1] = r1v;
  }
}

extern "C" void kernel_launch(void* const* d_in, const int* in_sizes, int n_in,
                              void* d_out, int out_size, void* d_ws, size_t ws_size,
                              hipStream_t stream) {
  const float* X = (const float*)d_in[0];
  const float* gaps = (const float*)d_in[1];
  const int* nnc = (const int*)d_in[2];
  float* out = (float*)d_out;

  float* sqv = (float*)d_ws;                                  // 32 KB
  uint4* Xb4 = (uint4*)((char*)d_ws + 32768);                 // 8 MB bf16 X
  uint* ckey = (uint*)((char*)d_ws + 32768 + 8388608);        // 4 MB candidates

  cvtsq_kernel<<<TT / 4, 256, 0, stream>>>(X, Xb4, sqv);
  gemm_topk<<<1024, 256, 0, stream>>>((const ushort*)Xb4, sqv, ckey);
  refine_gen<<<TT / 4, 256, 0, stream>>>(X, ckey, gaps, nnc, out);
}